// Round 1
// baseline (396.710 us; speedup 1.0000x reference)
//
#include <hip/hip_runtime.h>
#include <math.h>

#define N_NODES 40000
#define N_EDGES 640000
#define ET (N_EDGES + N_NODES)   // 680000 total edges incl. self-loops

__device__ __forceinline__ float wave_red_sum(float v) {
#pragma unroll
  for (int m = 32; m >= 1; m >>= 1) v += __shfl_xor(v, m, 64);
  return v;
}
__device__ __forceinline__ float wave_red_max(float v) {
#pragma unroll
  for (int m = 32; m >= 1; m >>= 1) v = fmaxf(v, __shfl_xor(v, m, 64));
  return v;
}

// ---------------- CSR build ----------------
__global__ void k_hist(const int* __restrict__ ei, int* __restrict__ deg) {
  int i = blockIdx.x * blockDim.x + threadIdx.x;
  if (i >= ET) return;
  int d = (i < N_EDGES) ? ei[N_EDGES + i] : (i - N_EDGES);
  atomicAdd(&deg[d], 1);
}

__global__ __launch_bounds__(1024) void k_scan(const int* __restrict__ deg,
                                               int* __restrict__ off,
                                               int* __restrict__ cur) {
  __shared__ int sd[1024];
  __shared__ int carry_s;
  int t = threadIdx.x;
  if (t == 0) carry_s = 0;
  __syncthreads();
  for (int base = 0; base < N_NODES; base += 1024) {
    int idx = base + t;
    int v = (idx < N_NODES) ? deg[idx] : 0;
    sd[t] = v;
    __syncthreads();
#pragma unroll
    for (int o = 1; o < 1024; o <<= 1) {
      int add = (t >= o) ? sd[t - o] : 0;
      __syncthreads();
      sd[t] += add;
      __syncthreads();
    }
    int carry = carry_s;
    int excl = carry + sd[t] - v;   // exclusive prefix
    if (idx < N_NODES) { off[idx] = excl; cur[idx] = excl; }
    __syncthreads();
    if (t == 1023) carry_s = carry + sd[1023];
    __syncthreads();
  }
  if (t == 0) off[N_NODES] = carry_s;
}

__global__ void k_fill(const int* __restrict__ ei, int* __restrict__ cur,
                       int* __restrict__ csr_src) {
  int i = blockIdx.x * blockDim.x + threadIdx.x;
  if (i >= ET) return;
  int s, d;
  if (i < N_EDGES) { s = ei[i]; d = ei[N_EDGES + i]; }
  else             { s = d = i - N_EDGES; }
  int p = atomicAdd(&cur[d], 1);
  csr_src[p] = s;
}

// ---------------- Layer 1: GEMM (x @ W1) + attention dots ----------------
// block = 128 threads (thread t = output col t), 32 nodes per block
__global__ __launch_bounds__(128) void k_gemm1(
    const float* __restrict__ x, const float* __restrict__ W1,
    const float* __restrict__ asv, const float* __restrict__ adv,
    float* __restrict__ h1, float* __restrict__ a_s, float* __restrict__ a_d) {
  __shared__ float xs[32 * 128];
  int t = threadIdx.x;
  int n0 = blockIdx.x * 32;
  const float4* xg = (const float4*)(x + (size_t)n0 * 128);
  float4* xs4 = (float4*)xs;
#pragma unroll
  for (int i = 0; i < 8; i++) xs4[t + i * 128] = xg[t + i * 128];
  __syncthreads();

  float acc[32];
#pragma unroll
  for (int m = 0; m < 32; m++) acc[m] = 0.f;

  for (int k4 = 0; k4 < 32; k4++) {
    float w0 = W1[(4 * k4 + 0) * 128 + t];
    float w1 = W1[(4 * k4 + 1) * 128 + t];
    float w2 = W1[(4 * k4 + 2) * 128 + t];
    float w3 = W1[(4 * k4 + 3) * 128 + t];
#pragma unroll
    for (int m = 0; m < 32; m++) {
      float4 xv = xs4[m * 32 + k4];
      acc[m] = fmaf(xv.x, w0, acc[m]);
      acc[m] = fmaf(xv.y, w1, acc[m]);
      acc[m] = fmaf(xv.z, w2, acc[m]);
      acc[m] = fmaf(xv.w, w3, acc[m]);
    }
  }

  float av_s = asv[t];   // att_src1 flat [2*64] == feature index t
  float av_d = adv[t];
  int h = t >> 6, lane = t & 63;
#pragma unroll 4
  for (int m = 0; m < 32; m++) {
    h1[(size_t)(n0 + m) * 128 + t] = acc[m];
    float rs = wave_red_sum(acc[m] * av_s);
    float rd = wave_red_sum(acc[m] * av_d);
    if (lane == 0) {
      a_s[(n0 + m) * 2 + h] = rs;
      a_d[(n0 + m) * 2 + h] = rd;
    }
  }
}

// ---------------- Layer 1: segment softmax + aggregation + ELU ----------------
// block = 128 threads, one node per block. wave0 = head0, wave1 = head1 for logits.
__global__ __launch_bounds__(128) void k_agg1(
    const int* __restrict__ off, const int* __restrict__ csr_src,
    const float* __restrict__ a_s, const float* __restrict__ a_d,
    const float* __restrict__ h1, const float* __restrict__ b1,
    float* __restrict__ exw, float* __restrict__ hout) {
  int v = blockIdx.x;
  int t = threadIdx.x;
  int lane = t & 63, h = t >> 6;
  int beg = off[v], end = off[v + 1];
  float adv = a_d[v * 2 + h];

  // pass 1: max logit per head
  float m = -1e30f;
  for (int i = beg + lane; i < end; i += 64) {
    int s = csr_src[i];
    float e = a_s[s * 2 + h] + adv;
    e = (e >= 0.f) ? e : 0.2f * e;
    m = fmaxf(m, e);
  }
  m = wave_red_max(m);

  // pass 2: exp + sum, stage exp values (planar by head)
  float sum = 0.f;
  for (int i = beg + lane; i < end; i += 64) {
    int s = csr_src[i];
    float e = a_s[s * 2 + h] + adv;
    e = (e >= 0.f) ? e : 0.2f * e;
    float ex = __expf(e - m);
    exw[(size_t)h * ET + i] = ex;
    sum += ex;
  }
  sum = wave_red_sum(sum);
  __shared__ float sh[2];
  if (lane == 0) sh[h] = sum;
  __syncthreads();
  float inv = 1.f / (sh[h] + 1e-16f);

  // pass 3: feature accumulation (thread t owns feature t)
  const float* exh = exw + (size_t)h * ET;
  float acc = 0.f;
  for (int i = beg; i < end; i++) {
    int s = csr_src[i];
    acc = fmaf(exh[i], h1[(size_t)s * 128 + t], acc);
  }
  float o = acc * inv + b1[t];
  hout[(size_t)v * 128 + t] = (o > 0.f) ? o : expm1f(o);   // ELU
}

// ---------------- Layer 2: GEMM (h @ W2) + attention dots ----------------
// one wave per node, block = 256 (4 nodes/block)
__global__ __launch_bounds__(256) void k_gemm2(
    const float* __restrict__ hin, const float* __restrict__ W2,
    const float* __restrict__ asv, const float* __restrict__ adv,
    float* __restrict__ h2, float* __restrict__ a_s2, float* __restrict__ a_d2) {
  int t = threadIdx.x;
  int lane = t & 63;
  int n = blockIdx.x * 4 + (t >> 6);
  float4 w_lo = *(const float4*)(W2 + lane * 4);
  float4 w_hi = *(const float4*)(W2 + (64 + lane) * 4);
  float x_lo = hin[(size_t)n * 128 + lane];
  float x_hi = hin[(size_t)n * 128 + 64 + lane];
  float4 p;
  p.x = fmaf(x_lo, w_lo.x, x_hi * w_hi.x);
  p.y = fmaf(x_lo, w_lo.y, x_hi * w_hi.y);
  p.z = fmaf(x_lo, w_lo.z, x_hi * w_hi.z);
  p.w = fmaf(x_lo, w_lo.w, x_hi * w_hi.w);
  p.x = wave_red_sum(p.x);
  p.y = wave_red_sum(p.y);
  p.z = wave_red_sum(p.z);
  p.w = wave_red_sum(p.w);
  if (lane == 0) {
    *(float4*)(h2 + (size_t)n * 4) = p;
    a_s2[n] = p.x * asv[0] + p.y * asv[1] + p.z * asv[2] + p.w * asv[3];
    a_d2[n] = p.x * adv[0] + p.y * adv[1] + p.z * adv[2] + p.w * adv[3];
  }
}

// ---------------- Layer 2: fused segment softmax + aggregation + row softmax ----------------
// one wave per node
__global__ __launch_bounds__(64) void k_agg2(
    const int* __restrict__ off, const int* __restrict__ csr_src,
    const float* __restrict__ a_s, const float* __restrict__ a_d,
    const float* __restrict__ h2, const float* __restrict__ b2,
    float* __restrict__ out) {
  int v = blockIdx.x;
  int lane = threadIdx.x;
  int beg = off[v], end = off[v + 1];
  float adv = a_d[v];

  float m = -1e30f;
  for (int i = beg + lane; i < end; i += 64) {
    float e = a_s[csr_src[i]] + adv;
    e = (e >= 0.f) ? e : 0.2f * e;
    m = fmaxf(m, e);
  }
  m = wave_red_max(m);

  float sum = 0.f;
  float4 acc = {0.f, 0.f, 0.f, 0.f};
  for (int i = beg + lane; i < end; i += 64) {
    int s = csr_src[i];
    float e = a_s[s] + adv;
    e = (e >= 0.f) ? e : 0.2f * e;
    float ex = __expf(e - m);
    sum += ex;
    float4 hv = *(const float4*)(h2 + (size_t)s * 4);
    acc.x = fmaf(ex, hv.x, acc.x);
    acc.y = fmaf(ex, hv.y, acc.y);
    acc.z = fmaf(ex, hv.z, acc.z);
    acc.w = fmaf(ex, hv.w, acc.w);
  }
  sum = wave_red_sum(sum);
  acc.x = wave_red_sum(acc.x);
  acc.y = wave_red_sum(acc.y);
  acc.z = wave_red_sum(acc.z);
  acc.w = wave_red_sum(acc.w);

  if (lane == 0) {
    float invd = 1.f / (sum + 1e-16f);
    float o0 = acc.x * invd + b2[0];
    float o1 = acc.y * invd + b2[1];
    float o2 = acc.z * invd + b2[2];
    float o3 = acc.w * invd + b2[3];
    float mx = fmaxf(fmaxf(o0, o1), fmaxf(o2, o3));
    float e0 = __expf(o0 - mx), e1 = __expf(o1 - mx);
    float e2 = __expf(o2 - mx), e3 = __expf(o3 - mx);
    float s4 = e0 + e1 + e2 + e3;
    float4 r = {e0 / s4, e1 / s4, e2 / s4, e3 / s4};
    *(float4*)(out + (size_t)v * 4) = r;
  }
}

extern "C" void kernel_launch(void* const* d_in, const int* in_sizes, int n_in,
                              void* d_out, int out_size, void* d_ws, size_t ws_size,
                              hipStream_t stream) {
  const float* x   = (const float*)d_in[0];
  const int*   ei  = (const int*)d_in[1];   // [2, E]: row0 = src, row1 = dst
  // d_in[2] (weights) unused by reference
  const float* W1  = (const float*)d_in[3];
  const float* as1 = (const float*)d_in[4];
  const float* ad1 = (const float*)d_in[5];
  const float* b1  = (const float*)d_in[6];
  const float* W2  = (const float*)d_in[7];
  const float* as2 = (const float*)d_in[8];
  const float* ad2 = (const float*)d_in[9];
  const float* b2  = (const float*)d_in[10];
  float* out = (float*)d_out;

  char* w = (char*)d_ws;
  auto alloc = [&](size_t bytes) {
    char* p = w;
    w += (bytes + 255) & ~(size_t)255;
    return p;
  };
  int*   deg     = (int*)alloc((size_t)N_NODES * 4);
  int*   off     = (int*)alloc((size_t)(N_NODES + 1) * 4);
  int*   cur     = (int*)alloc((size_t)N_NODES * 4);
  int*   csr_src = (int*)alloc((size_t)ET * 4);
  float* h1      = (float*)alloc((size_t)N_NODES * 128 * 4);
  float* a_s1w   = (float*)alloc((size_t)N_NODES * 2 * 4);
  float* a_d1w   = (float*)alloc((size_t)N_NODES * 2 * 4);
  float* exw     = (float*)alloc((size_t)ET * 2 * 4);
  float* helu    = (float*)alloc((size_t)N_NODES * 128 * 4);
  float* h2      = (float*)alloc((size_t)N_NODES * 4 * 4);
  float* a_s2w   = (float*)alloc((size_t)N_NODES * 4);
  float* a_d2w   = (float*)alloc((size_t)N_NODES * 4);

  hipMemsetAsync(deg, 0, (size_t)N_NODES * 4, stream);
  k_hist<<<(ET + 255) / 256, 256, 0, stream>>>(ei, deg);
  k_scan<<<1, 1024, 0, stream>>>(deg, off, cur);
  k_fill<<<(ET + 255) / 256, 256, 0, stream>>>(ei, cur, csr_src);

  k_gemm1<<<N_NODES / 32, 128, 0, stream>>>(x, W1, as1, ad1, h1, a_s1w, a_d1w);
  k_agg1<<<N_NODES, 128, 0, stream>>>(off, csr_src, a_s1w, a_d1w, h1, b1, exw, helu);
  k_gemm2<<<N_NODES / 4, 256, 0, stream>>>(helu, W2, as2, ad2, h2, a_s2w, a_d2w);
  k_agg2<<<N_NODES, 64, 0, stream>>>(off, csr_src, a_s2w, a_d2w, h2, b2, out);
}

// Round 2
// 363.266 us; speedup vs baseline: 1.0921x; 1.0921x over previous
//
#include <hip/hip_runtime.h>
#include <hip/hip_bf16.h>
#include <math.h>

#define N_NODES 40000
#define N_EDGES 640000
#define ET (N_EDGES + N_NODES)   // 680000 total edges incl. self-loops

__device__ __forceinline__ float wave_red_sum(float v) {
#pragma unroll
  for (int m = 32; m >= 1; m >>= 1) v += __shfl_xor(v, m, 64);
  return v;
}

// ---------------- CSR build ----------------
__global__ void k_hist(const int* __restrict__ ei, int* __restrict__ deg) {
  int i = blockIdx.x * blockDim.x + threadIdx.x;
  if (i >= ET) return;
  int d = (i < N_EDGES) ? ei[N_EDGES + i] : (i - N_EDGES);
  atomicAdd(&deg[d], 1);
}

// single block, chunk-per-thread scan: 1024 threads x 40 nodes
__global__ __launch_bounds__(1024) void k_scan(const int* __restrict__ deg,
                                               int* __restrict__ off,
                                               int* __restrict__ cur) {
  const int CH = 40;   // 1024*40 = 40960 >= 40000
  int t = threadIdx.x;
  int base = t * CH;
  int d[CH];
  int local = 0;
#pragma unroll
  for (int j = 0; j < CH; j++) {
    int idx = base + j;
    d[j] = (idx < N_NODES) ? deg[idx] : 0;
    local += d[j];
  }
  // block exclusive scan of per-thread sums
  int lane = t & 63, w = t >> 6;
  int v = local;
#pragma unroll
  for (int o = 1; o < 64; o <<= 1) {
    int u = __shfl_up(v, o, 64);
    if (lane >= o) v += u;
  }
  __shared__ int wsum[16], wpre[16];
  if (lane == 63) wsum[w] = v;
  __syncthreads();
  if (t == 0) {
    int r = 0;
#pragma unroll
    for (int k = 0; k < 16; k++) { wpre[k] = r; r += wsum[k]; }
    off[N_NODES] = r;
  }
  __syncthreads();
  int run = wpre[w] + v - local;   // exclusive prefix of this thread's chunk
#pragma unroll
  for (int j = 0; j < CH; j++) {
    int idx = base + j;
    if (idx < N_NODES) { off[idx] = run; cur[idx] = run; }
    run += d[j];
  }
}

__global__ void k_fill(const int* __restrict__ ei, int* __restrict__ cur,
                       int* __restrict__ csr_src) {
  int i = blockIdx.x * blockDim.x + threadIdx.x;
  if (i >= ET) return;
  int s, d;
  if (i < N_EDGES) { s = ei[i]; d = ei[N_EDGES + i]; }
  else             { s = d = i - N_EDGES; }
  int p = atomicAdd(&cur[d], 1);
  csr_src[p] = s;
}

// ---------------- Layer 1: GEMM (x @ W1) + attention dots ----------------
// block = 128 threads (thread t = output col t), 32 nodes per block.
// x loads are wave-uniform -> scalar loads; W column per-thread in VGPRs.
__global__ __launch_bounds__(128) void k_gemm1(
    const float* __restrict__ x, const float* __restrict__ W1,
    const float* __restrict__ asv, const float* __restrict__ adv,
    __hip_bfloat16* __restrict__ h1b, float* __restrict__ a_s, float* __restrict__ a_d) {
  int t = threadIdx.x;
  int n0 = blockIdx.x * 32;
  float acc[32];
#pragma unroll
  for (int m = 0; m < 32; m++) acc[m] = 0.f;

  for (int k = 0; k < 128; k += 4) {
    float w0 = W1[(k + 0) * 128 + t];
    float w1 = W1[(k + 1) * 128 + t];
    float w2 = W1[(k + 2) * 128 + t];
    float w3 = W1[(k + 3) * 128 + t];
#pragma unroll
    for (int m = 0; m < 32; m++) {
      const float4 xv = *(const float4*)(x + (size_t)(n0 + m) * 128 + k);  // uniform -> s_load
      acc[m] = fmaf(xv.x, w0, acc[m]);
      acc[m] = fmaf(xv.y, w1, acc[m]);
      acc[m] = fmaf(xv.z, w2, acc[m]);
      acc[m] = fmaf(xv.w, w3, acc[m]);
    }
  }

  float av_s = asv[t];
  float av_d = adv[t];
  int h = t >> 6, lane = t & 63;
#pragma unroll 4
  for (int m = 0; m < 32; m++) {
    h1b[(size_t)(n0 + m) * 128 + t] = __float2bfloat16(acc[m]);
    float rs = wave_red_sum(acc[m] * av_s);
    float rd = wave_red_sum(acc[m] * av_d);
    if (lane == 0) {
      a_s[(n0 + m) * 2 + h] = rs;
      a_d[(n0 + m) * 2 + h] = rd;
    }
  }
}

// ---------------- Layer 1 agg (single pass) + ELU + fused layer-2 GEMM ----------------
// block = 128 threads, one node per block. thread t = feature t, head = t>>6.
__global__ __launch_bounds__(128) void k_agg1(
    const int* __restrict__ off, const int* __restrict__ csr_src,
    const float* __restrict__ a_s, const float* __restrict__ a_d,
    const __hip_bfloat16* __restrict__ h1b, const float* __restrict__ b1,
    const float* __restrict__ W2, const float* __restrict__ as2,
    const float* __restrict__ ad2,
    float* __restrict__ h2, float* __restrict__ a_s2, float* __restrict__ a_d2) {
  int v = blockIdx.x;
  int t = threadIdx.x;
  int h = t >> 6, lane = t & 63;
  int beg = off[v], end = off[v + 1];
  float2 advv = *(const float2*)(a_d + 2 * v);
  float adh = h ? advv.y : advv.x;

  float sum = 0.f;
  float acc0 = 0.f, acc1 = 0.f, acc2 = 0.f, acc3 = 0.f;
  int i = beg;
  for (; i + 4 <= end; i += 4) {
    int s0 = csr_src[i], s1 = csr_src[i + 1], s2 = csr_src[i + 2], s3 = csr_src[i + 3];
    float2 A0 = *(const float2*)(a_s + 2 * s0);
    float2 A1 = *(const float2*)(a_s + 2 * s1);
    float2 A2 = *(const float2*)(a_s + 2 * s2);
    float2 A3 = *(const float2*)(a_s + 2 * s3);
    float e0 = (h ? A0.y : A0.x) + adh; e0 = (e0 >= 0.f) ? e0 : 0.2f * e0;
    float e1 = (h ? A1.y : A1.x) + adh; e1 = (e1 >= 0.f) ? e1 : 0.2f * e1;
    float e2 = (h ? A2.y : A2.x) + adh; e2 = (e2 >= 0.f) ? e2 : 0.2f * e2;
    float e3 = (h ? A3.y : A3.x) + adh; e3 = (e3 >= 0.f) ? e3 : 0.2f * e3;
    float x0 = __expf(e0), x1 = __expf(e1), x2 = __expf(e2), x3 = __expf(e3);
    sum += (x0 + x1) + (x2 + x3);
    acc0 = fmaf(x0, __bfloat162float(h1b[(size_t)s0 * 128 + t]), acc0);
    acc1 = fmaf(x1, __bfloat162float(h1b[(size_t)s1 * 128 + t]), acc1);
    acc2 = fmaf(x2, __bfloat162float(h1b[(size_t)s2 * 128 + t]), acc2);
    acc3 = fmaf(x3, __bfloat162float(h1b[(size_t)s3 * 128 + t]), acc3);
  }
  for (; i < end; i++) {
    int s = csr_src[i];
    float2 A = *(const float2*)(a_s + 2 * s);
    float e = (h ? A.y : A.x) + adh; e = (e >= 0.f) ? e : 0.2f * e;
    float ex = __expf(e);
    sum += ex;
    acc0 = fmaf(ex, __bfloat162float(h1b[(size_t)s * 128 + t]), acc0);
  }
  float acc = (acc0 + acc1) + (acc2 + acc3);
  float inv = 1.f / (sum + 1e-16f);
  float o = acc * inv + b1[t];
  o = (o > 0.f) ? o : expm1f(o);   // ELU

  // fused layer-2 GEMM: h2[v][j] = sum_t o[t] * W2[t][j]
  float4 w2v = *(const float4*)(W2 + t * 4);
  float p0 = wave_red_sum(o * w2v.x);
  float p1 = wave_red_sum(o * w2v.y);
  float p2 = wave_red_sum(o * w2v.z);
  float p3 = wave_red_sum(o * w2v.w);
  __shared__ float red[8];
  if (lane == 0) { red[h * 4 + 0] = p0; red[h * 4 + 1] = p1; red[h * 4 + 2] = p2; red[h * 4 + 3] = p3; }
  __syncthreads();
  if (t == 0) {
    float q0 = red[0] + red[4], q1 = red[1] + red[5];
    float q2 = red[2] + red[6], q3 = red[3] + red[7];
    float4 q = {q0, q1, q2, q3};
    *(float4*)(h2 + (size_t)v * 4) = q;
    a_s2[v] = q0 * as2[0] + q1 * as2[1] + q2 * as2[2] + q3 * as2[3];
    a_d2[v] = q0 * ad2[0] + q1 * ad2[1] + q2 * ad2[2] + q3 * ad2[3];
  }
}

// ---------------- Layer 2: fused segment softmax + aggregation + row softmax ----------------
// one wave per node, 4 nodes per block
__global__ __launch_bounds__(256) void k_agg2(
    const int* __restrict__ off, const int* __restrict__ csr_src,
    const float* __restrict__ a_s, const float* __restrict__ a_d,
    const float* __restrict__ h2, const float* __restrict__ b2,
    float* __restrict__ out) {
  int v = blockIdx.x * 4 + (threadIdx.x >> 6);
  int lane = threadIdx.x & 63;
  int beg = off[v], end = off[v + 1];
  float adv = a_d[v];

  float sum = 0.f;
  float4 acc = {0.f, 0.f, 0.f, 0.f};
  for (int i = beg + lane; i < end; i += 64) {
    int s = csr_src[i];
    float e = a_s[s] + adv;
    e = (e >= 0.f) ? e : 0.2f * e;
    float ex = __expf(e);
    sum += ex;
    float4 hv = *(const float4*)(h2 + (size_t)s * 4);
    acc.x = fmaf(ex, hv.x, acc.x);
    acc.y = fmaf(ex, hv.y, acc.y);
    acc.z = fmaf(ex, hv.z, acc.z);
    acc.w = fmaf(ex, hv.w, acc.w);
  }
  sum = wave_red_sum(sum);
  acc.x = wave_red_sum(acc.x);
  acc.y = wave_red_sum(acc.y);
  acc.z = wave_red_sum(acc.z);
  acc.w = wave_red_sum(acc.w);

  if (lane == 0) {
    float invd = 1.f / (sum + 1e-16f);
    float o0 = acc.x * invd + b2[0];
    float o1 = acc.y * invd + b2[1];
    float o2 = acc.z * invd + b2[2];
    float o3 = acc.w * invd + b2[3];
    float mx = fmaxf(fmaxf(o0, o1), fmaxf(o2, o3));
    float e0 = __expf(o0 - mx), e1 = __expf(o1 - mx);
    float e2 = __expf(o2 - mx), e3 = __expf(o3 - mx);
    float s4 = e0 + e1 + e2 + e3;
    float4 r = {e0 / s4, e1 / s4, e2 / s4, e3 / s4};
    *(float4*)(out + (size_t)v * 4) = r;
  }
}

extern "C" void kernel_launch(void* const* d_in, const int* in_sizes, int n_in,
                              void* d_out, int out_size, void* d_ws, size_t ws_size,
                              hipStream_t stream) {
  const float* x   = (const float*)d_in[0];
  const int*   ei  = (const int*)d_in[1];   // [2, E]: row0 = src, row1 = dst
  const float* W1  = (const float*)d_in[3];
  const float* as1 = (const float*)d_in[4];
  const float* ad1 = (const float*)d_in[5];
  const float* b1  = (const float*)d_in[6];
  const float* W2  = (const float*)d_in[7];
  const float* as2 = (const float*)d_in[8];
  const float* ad2 = (const float*)d_in[9];
  const float* b2  = (const float*)d_in[10];
  float* out = (float*)d_out;

  char* w = (char*)d_ws;
  auto alloc = [&](size_t bytes) {
    char* p = w;
    w += (bytes + 255) & ~(size_t)255;
    return p;
  };
  int*   deg     = (int*)alloc((size_t)N_NODES * 4);
  int*   off     = (int*)alloc((size_t)(N_NODES + 1) * 4);
  int*   cur     = (int*)alloc((size_t)N_NODES * 4);
  int*   csr_src = (int*)alloc((size_t)ET * 4);
  __hip_bfloat16* h1b = (__hip_bfloat16*)alloc((size_t)N_NODES * 128 * 2);
  float* a_s1w   = (float*)alloc((size_t)N_NODES * 2 * 4);
  float* a_d1w   = (float*)alloc((size_t)N_NODES * 2 * 4);
  float* h2      = (float*)alloc((size_t)N_NODES * 4 * 4);
  float* a_s2w   = (float*)alloc((size_t)N_NODES * 4);
  float* a_d2w   = (float*)alloc((size_t)N_NODES * 4);

  hipMemsetAsync(deg, 0, (size_t)N_NODES * 4, stream);
  k_hist<<<(ET + 255) / 256, 256, 0, stream>>>(ei, deg);
  k_scan<<<1, 1024, 0, stream>>>(deg, off, cur);
  k_fill<<<(ET + 255) / 256, 256, 0, stream>>>(ei, cur, csr_src);

  k_gemm1<<<N_NODES / 32, 128, 0, stream>>>(x, W1, as1, ad1, h1b, a_s1w, a_d1w);
  k_agg1<<<N_NODES, 128, 0, stream>>>(off, csr_src, a_s1w, a_d1w, h1b, b1,
                                      W2, as2, ad2, h2, a_s2w, a_d2w);
  k_agg2<<<N_NODES / 4, 256, 0, stream>>>(off, csr_src, a_s2w, a_d2w, h2, b2, out);
}

// Round 3
// 323.215 us; speedup vs baseline: 1.2274x; 1.1239x over previous
//
#include <hip/hip_runtime.h>
#include <hip/hip_bf16.h>
#include <math.h>

#define N_NODES 40000
#define N_EDGES 640000
#define ET (N_EDGES + N_NODES)   // 680000 total edges incl. self-loops

__device__ __forceinline__ float wave_red_sum(float v) {
#pragma unroll
  for (int m = 32; m >= 1; m >>= 1) v += __shfl_xor(v, m, 64);
  return v;
}
// reduce within 32-lane halves (head-split reduction)
__device__ __forceinline__ float half_red_sum(float v) {
#pragma unroll
  for (int m = 16; m >= 1; m >>= 1) v += __shfl_xor(v, m, 64);
  return v;
}

// ---------------- CSR build ----------------
__global__ void k_hist(const int* __restrict__ ei, int* __restrict__ deg) {
  int i = blockIdx.x * blockDim.x + threadIdx.x;
  if (i >= ET) return;
  int d = (i < N_EDGES) ? ei[N_EDGES + i] : (i - N_EDGES);
  atomicAdd(&deg[d], 1);
}

// single block, chunk-per-thread scan: 1024 threads x 40 nodes
__global__ __launch_bounds__(1024) void k_scan(const int* __restrict__ deg,
                                               int* __restrict__ off,
                                               int* __restrict__ cur) {
  const int CH = 40;   // 1024*40 = 40960 >= 40000
  int t = threadIdx.x;
  int base = t * CH;
  int d[CH];
  int local = 0;
#pragma unroll
  for (int j = 0; j < CH; j++) {
    int idx = base + j;
    d[j] = (idx < N_NODES) ? deg[idx] : 0;
    local += d[j];
  }
  int lane = t & 63, w = t >> 6;
  int v = local;
#pragma unroll
  for (int o = 1; o < 64; o <<= 1) {
    int u = __shfl_up(v, o, 64);
    if (lane >= o) v += u;
  }
  __shared__ int wsum[16], wpre[16];
  if (lane == 63) wsum[w] = v;
  __syncthreads();
  if (t == 0) {
    int r = 0;
#pragma unroll
    for (int k = 0; k < 16; k++) { wpre[k] = r; r += wsum[k]; }
    off[N_NODES] = r;
  }
  __syncthreads();
  int run = wpre[w] + v - local;   // exclusive prefix of this thread's chunk
#pragma unroll
  for (int j = 0; j < CH; j++) {
    int idx = base + j;
    if (idx < N_NODES) { off[idx] = run; cur[idx] = run; }
    run += d[j];
  }
}

__global__ void k_fill(const int* __restrict__ ei, int* __restrict__ cur,
                       int* __restrict__ csr_src) {
  int i = blockIdx.x * blockDim.x + threadIdx.x;
  if (i >= ET) return;
  int s, d;
  if (i < N_EDGES) { s = ei[i]; d = ei[N_EDGES + i]; }
  else             { s = d = i - N_EDGES; }
  int p = atomicAdd(&cur[d], 1);
  csr_src[p] = s;
}

// ---------------- Layer 1: GEMM (x @ W1) + attention dots ----------------
// block = 256 threads (4 waves), M-tile = 64 nodes (grid = 625 exactly).
// wave g owns nodes g*16..g*16+15; lane l owns cols 2l, 2l+1.
// lanes 0-31 -> head 0 cols, lanes 32-63 -> head 1 cols.
__global__ __launch_bounds__(256) void k_gemm1(
    const float* __restrict__ x, const float* __restrict__ W1,
    const float* __restrict__ asv, const float* __restrict__ adv,
    __hip_bfloat16* __restrict__ h1b, float* __restrict__ a_s, float* __restrict__ a_d) {
  __shared__ float xs[64 * 128];           // 32 KB
  int t = threadIdx.x;
  int n0 = blockIdx.x * 64;
  {
    const float4* xg = (const float4*)(x + (size_t)n0 * 128);
    float4* xs4 = (float4*)xs;
#pragma unroll
    for (int i = 0; i < 8; i++) xs4[t + i * 256] = xg[t + i * 256];
  }
  __syncthreads();

  int lane = t & 63;
  int g = t >> 6;                 // wave id = m-group
  int c0 = lane * 2;              // column pair
  const float4* xs4 = (const float4*)(xs + (size_t)g * 16 * 128);

  float2 acc[16];
#pragma unroll
  for (int j = 0; j < 16; j++) acc[j] = make_float2(0.f, 0.f);

  for (int k4 = 0; k4 < 32; k4++) {
    float2 w0 = *(const float2*)(W1 + (size_t)(4 * k4 + 0) * 128 + c0);
    float2 w1 = *(const float2*)(W1 + (size_t)(4 * k4 + 1) * 128 + c0);
    float2 w2 = *(const float2*)(W1 + (size_t)(4 * k4 + 2) * 128 + c0);
    float2 w3 = *(const float2*)(W1 + (size_t)(4 * k4 + 3) * 128 + c0);
#pragma unroll
    for (int j = 0; j < 16; j++) {
      float4 xv = xs4[j * 32 + k4];           // wave-uniform -> LDS broadcast
      acc[j].x = fmaf(xv.x, w0.x, acc[j].x);
      acc[j].y = fmaf(xv.x, w0.y, acc[j].y);
      acc[j].x = fmaf(xv.y, w1.x, acc[j].x);
      acc[j].y = fmaf(xv.y, w1.y, acc[j].y);
      acc[j].x = fmaf(xv.z, w2.x, acc[j].x);
      acc[j].y = fmaf(xv.z, w2.y, acc[j].y);
      acc[j].x = fmaf(xv.w, w3.x, acc[j].x);
      acc[j].y = fmaf(xv.w, w3.y, acc[j].y);
    }
  }

  float2 av_s = *(const float2*)(asv + c0);   // att flat [128] == col index
  float2 av_d = *(const float2*)(adv + c0);
  int head = lane >> 5;                        // 0 for cols<64, 1 for cols>=64
#pragma unroll 4
  for (int j = 0; j < 16; j++) {
    int n = n0 + g * 16 + j;
    __hip_bfloat162 hv;
    hv.x = __float2bfloat16(acc[j].x);
    hv.y = __float2bfloat16(acc[j].y);
    *(__hip_bfloat162*)(h1b + (size_t)n * 128 + c0) = hv;
    float rs = half_red_sum(acc[j].x * av_s.x + acc[j].y * av_s.y);
    float rd = half_red_sum(acc[j].x * av_d.x + acc[j].y * av_d.y);
    if ((lane & 31) == 0) {
      a_s[n * 2 + head] = rs;
      a_d[n * 2 + head] = rd;
    }
  }
}

// ---------------- Layer 1 agg (single pass) + ELU + fused layer-2 GEMM ----------------
__global__ __launch_bounds__(128) void k_agg1(
    const int* __restrict__ off, const int* __restrict__ csr_src,
    const float* __restrict__ a_s, const float* __restrict__ a_d,
    const __hip_bfloat16* __restrict__ h1b, const float* __restrict__ b1,
    const float* __restrict__ W2, const float* __restrict__ as2,
    const float* __restrict__ ad2,
    float* __restrict__ h2, float* __restrict__ a_s2, float* __restrict__ a_d2) {
  int v = blockIdx.x;
  int t = threadIdx.x;
  int h = t >> 6, lane = t & 63;
  int beg = off[v], end = off[v + 1];
  float2 advv = *(const float2*)(a_d + 2 * v);
  float adh = h ? advv.y : advv.x;

  float sum = 0.f;
  float acc0 = 0.f, acc1 = 0.f, acc2 = 0.f, acc3 = 0.f;
  int i = beg;
  for (; i + 4 <= end; i += 4) {
    int s0 = csr_src[i], s1 = csr_src[i + 1], s2 = csr_src[i + 2], s3 = csr_src[i + 3];
    float2 A0 = *(const float2*)(a_s + 2 * s0);
    float2 A1 = *(const float2*)(a_s + 2 * s1);
    float2 A2 = *(const float2*)(a_s + 2 * s2);
    float2 A3 = *(const float2*)(a_s + 2 * s3);
    float e0 = (h ? A0.y : A0.x) + adh; e0 = (e0 >= 0.f) ? e0 : 0.2f * e0;
    float e1 = (h ? A1.y : A1.x) + adh; e1 = (e1 >= 0.f) ? e1 : 0.2f * e1;
    float e2 = (h ? A2.y : A2.x) + adh; e2 = (e2 >= 0.f) ? e2 : 0.2f * e2;
    float e3 = (h ? A3.y : A3.x) + adh; e3 = (e3 >= 0.f) ? e3 : 0.2f * e3;
    float x0 = __expf(e0), x1 = __expf(e1), x2 = __expf(e2), x3 = __expf(e3);
    sum += (x0 + x1) + (x2 + x3);
    acc0 = fmaf(x0, __bfloat162float(h1b[(size_t)s0 * 128 + t]), acc0);
    acc1 = fmaf(x1, __bfloat162float(h1b[(size_t)s1 * 128 + t]), acc1);
    acc2 = fmaf(x2, __bfloat162float(h1b[(size_t)s2 * 128 + t]), acc2);
    acc3 = fmaf(x3, __bfloat162float(h1b[(size_t)s3 * 128 + t]), acc3);
  }
  for (; i < end; i++) {
    int s = csr_src[i];
    float2 A = *(const float2*)(a_s + 2 * s);
    float e = (h ? A.y : A.x) + adh; e = (e >= 0.f) ? e : 0.2f * e;
    float ex = __expf(e);
    sum += ex;
    acc0 = fmaf(ex, __bfloat162float(h1b[(size_t)s * 128 + t]), acc0);
  }
  float acc = (acc0 + acc1) + (acc2 + acc3);
  float inv = 1.f / (sum + 1e-16f);
  float o = acc * inv + b1[t];
  o = (o > 0.f) ? o : expm1f(o);   // ELU

  float4 w2v = *(const float4*)(W2 + t * 4);
  float p0 = wave_red_sum(o * w2v.x);
  float p1 = wave_red_sum(o * w2v.y);
  float p2 = wave_red_sum(o * w2v.z);
  float p3 = wave_red_sum(o * w2v.w);
  __shared__ float red[8];
  if (lane == 0) { red[h * 4 + 0] = p0; red[h * 4 + 1] = p1; red[h * 4 + 2] = p2; red[h * 4 + 3] = p3; }
  __syncthreads();
  if (t == 0) {
    float q0 = red[0] + red[4], q1 = red[1] + red[5];
    float q2 = red[2] + red[6], q3 = red[3] + red[7];
    float4 q = {q0, q1, q2, q3};
    *(float4*)(h2 + (size_t)v * 4) = q;
    a_s2[v] = q0 * as2[0] + q1 * as2[1] + q2 * as2[2] + q3 * as2[3];
    a_d2[v] = q0 * ad2[0] + q1 * ad2[1] + q2 * ad2[2] + q3 * ad2[3];
  }
}

// ---------------- Layer 2: fused segment softmax + aggregation + row softmax ----------------
__global__ __launch_bounds__(256) void k_agg2(
    const int* __restrict__ off, const int* __restrict__ csr_src,
    const float* __restrict__ a_s, const float* __restrict__ a_d,
    const float* __restrict__ h2, const float* __restrict__ b2,
    float* __restrict__ out) {
  int v = blockIdx.x * 4 + (threadIdx.x >> 6);
  int lane = threadIdx.x & 63;
  int beg = off[v], end = off[v + 1];
  float adv = a_d[v];

  float sum = 0.f;
  float4 acc = {0.f, 0.f, 0.f, 0.f};
  for (int i = beg + lane; i < end; i += 64) {
    int s = csr_src[i];
    float e = a_s[s] + adv;
    e = (e >= 0.f) ? e : 0.2f * e;
    float ex = __expf(e);
    sum += ex;
    float4 hv = *(const float4*)(h2 + (size_t)s * 4);
    acc.x = fmaf(ex, hv.x, acc.x);
    acc.y = fmaf(ex, hv.y, acc.y);
    acc.z = fmaf(ex, hv.z, acc.z);
    acc.w = fmaf(ex, hv.w, acc.w);
  }
  sum = wave_red_sum(sum);
  acc.x = wave_red_sum(acc.x);
  acc.y = wave_red_sum(acc.y);
  acc.z = wave_red_sum(acc.z);
  acc.w = wave_red_sum(acc.w);

  if (lane == 0) {
    float invd = 1.f / (sum + 1e-16f);
    float o0 = acc.x * invd + b2[0];
    float o1 = acc.y * invd + b2[1];
    float o2 = acc.z * invd + b2[2];
    float o3 = acc.w * invd + b2[3];
    float mx = fmaxf(fmaxf(o0, o1), fmaxf(o2, o3));
    float e0 = __expf(o0 - mx), e1 = __expf(o1 - mx);
    float e2 = __expf(o2 - mx), e3 = __expf(o3 - mx);
    float s4 = e0 + e1 + e2 + e3;
    float4 r = {e0 / s4, e1 / s4, e2 / s4, e3 / s4};
    *(float4*)(out + (size_t)v * 4) = r;
  }
}

extern "C" void kernel_launch(void* const* d_in, const int* in_sizes, int n_in,
                              void* d_out, int out_size, void* d_ws, size_t ws_size,
                              hipStream_t stream) {
  const float* x   = (const float*)d_in[0];
  const int*   ei  = (const int*)d_in[1];   // [2, E]: row0 = src, row1 = dst
  const float* W1  = (const float*)d_in[3];
  const float* as1 = (const float*)d_in[4];
  const float* ad1 = (const float*)d_in[5];
  const float* b1  = (const float*)d_in[6];
  const float* W2  = (const float*)d_in[7];
  const float* as2 = (const float*)d_in[8];
  const float* ad2 = (const float*)d_in[9];
  const float* b2  = (const float*)d_in[10];
  float* out = (float*)d_out;

  char* w = (char*)d_ws;
  auto alloc = [&](size_t bytes) {
    char* p = w;
    w += (bytes + 255) & ~(size_t)255;
    return p;
  };
  int*   deg     = (int*)alloc((size_t)N_NODES * 4);
  int*   off     = (int*)alloc((size_t)(N_NODES + 1) * 4);
  int*   cur     = (int*)alloc((size_t)N_NODES * 4);
  int*   csr_src = (int*)alloc((size_t)ET * 4);
  __hip_bfloat16* h1b = (__hip_bfloat16*)alloc((size_t)N_NODES * 128 * 2);
  float* a_s1w   = (float*)alloc((size_t)N_NODES * 2 * 4);
  float* a_d1w   = (float*)alloc((size_t)N_NODES * 2 * 4);
  float* h2      = (float*)alloc((size_t)N_NODES * 4 * 4);
  float* a_s2w   = (float*)alloc((size_t)N_NODES * 4);
  float* a_d2w   = (float*)alloc((size_t)N_NODES * 4);

  hipMemsetAsync(deg, 0, (size_t)N_NODES * 4, stream);
  k_hist<<<(ET + 255) / 256, 256, 0, stream>>>(ei, deg);
  k_scan<<<1, 1024, 0, stream>>>(deg, off, cur);
  k_fill<<<(ET + 255) / 256, 256, 0, stream>>>(ei, cur, csr_src);

  k_gemm1<<<N_NODES / 64, 256, 0, stream>>>(x, W1, as1, ad1, h1b, a_s1w, a_d1w);
  k_agg1<<<N_NODES, 128, 0, stream>>>(off, csr_src, a_s1w, a_d1w, h1b, b1,
                                      W2, as2, ad2, h2, a_s2w, a_d2w);
  k_agg2<<<N_NODES / 4, 256, 0, stream>>>(off, csr_src, a_s2w, a_d2w, h2, b2, out);
}

// Round 4
// 268.694 us; speedup vs baseline: 1.4764x; 1.2029x over previous
//
#include <hip/hip_runtime.h>
#include <hip/hip_bf16.h>
#include <math.h>

#define N_NODES 40000
#define N_EDGES 640000
#define ET (N_EDGES + N_NODES)   // 680000 total edges incl. self-loops
#define SCAN_BLOCKS 40
#define SCAN_CHUNK 1000          // 40 * 1000 = 40000

__device__ __forceinline__ float wave_red_sum(float v) {
#pragma unroll
  for (int m = 32; m >= 1; m >>= 1) v += __shfl_xor(v, m, 64);
  return v;
}
__device__ __forceinline__ int wave_red_sum_i(int v) {
#pragma unroll
  for (int m = 32; m >= 1; m >>= 1) v += __shfl_xor(v, m, 64);
  return v;
}
// reduce within 32-lane halves (head-split reduction)
__device__ __forceinline__ float half_red_sum(float v) {
#pragma unroll
  for (int m = 16; m >= 1; m >>= 1) v += __shfl_xor(v, m, 64);
  return v;
}

// ---------------- CSR build ----------------
__global__ void k_hist(const int* __restrict__ ei, int* __restrict__ deg) {
  int i = blockIdx.x * blockDim.x + threadIdx.x;
  if (i >= ET) return;
  int d = (i < N_EDGES) ? ei[N_EDGES + i] : (i - N_EDGES);
  atomicAdd(&deg[d], 1);
}

// hierarchical scan, stage A: per-block sums of 1000-element chunks
__global__ __launch_bounds__(1024) void k_scanA(const int* __restrict__ deg,
                                                int* __restrict__ blocksum) {
  int t = threadIdx.x;
  int idx = blockIdx.x * SCAN_CHUNK + t;
  int v = (t < SCAN_CHUNK) ? deg[idx] : 0;
  int lane = t & 63, w = t >> 6;
  int s = wave_red_sum_i(v);
  __shared__ int ws[16];
  if (lane == 0) ws[w] = s;
  __syncthreads();
  if (t == 0) {
    int r = 0;
#pragma unroll
    for (int k = 0; k < 16; k++) r += ws[k];
    blocksum[blockIdx.x] = r;
  }
}

// stage B: per-block exclusive scan + carry from blocksum prefix
__global__ __launch_bounds__(1024) void k_scanB(const int* __restrict__ deg,
                                                const int* __restrict__ blocksum,
                                                int* __restrict__ off,
                                                int* __restrict__ cur) {
  int t = threadIdx.x;
  int b = blockIdx.x;
  int lane = t & 63, w = t >> 6;
  __shared__ int carry_s;
  __shared__ int ws[16];
  if (w == 0) {
    int bs = (lane < b) ? blocksum[lane] : 0;   // b <= 40 <= 64 lanes
    int c = wave_red_sum_i(bs);
    if (lane == 0) carry_s = c;
  }
  int idx = b * SCAN_CHUNK + t;
  int v = (t < SCAN_CHUNK) ? deg[idx] : 0;
  // inclusive wave scan
  int p = v;
#pragma unroll
  for (int o = 1; o < 64; o <<= 1) {
    int u = __shfl_up(p, o, 64);
    if (lane >= o) p += u;
  }
  if (lane == 63) ws[w] = p;
  __syncthreads();
  if (t == 0) {
    int r = 0;
#pragma unroll
    for (int k = 0; k < 16; k++) { int x = ws[k]; ws[k] = r; r += x; }
  }
  __syncthreads();
  int excl = carry_s + ws[w] + p - v;
  if (t < SCAN_CHUNK) { off[idx] = excl; cur[idx] = excl; }
  if (b == SCAN_BLOCKS - 1 && t == SCAN_CHUNK - 1) off[N_NODES] = excl + v;
}

__global__ void k_fill(const int* __restrict__ ei, int* __restrict__ cur,
                       int* __restrict__ csr_src) {
  int i = blockIdx.x * blockDim.x + threadIdx.x;
  if (i >= ET) return;
  int s, d;
  if (i < N_EDGES) { s = ei[i]; d = ei[N_EDGES + i]; }
  else             { s = d = i - N_EDGES; }
  int p = atomicAdd(&cur[d], 1);
  csr_src[p] = s;
}

// ---------------- Layer 1: GEMM (x @ W1) + attention dots ----------------
// block = 256 threads (4 waves), M-tile = 64 nodes (grid = 625 exactly).
__global__ __launch_bounds__(256) void k_gemm1(
    const float* __restrict__ x, const float* __restrict__ W1,
    const float* __restrict__ asv, const float* __restrict__ adv,
    __hip_bfloat16* __restrict__ h1b, float* __restrict__ a_s, float* __restrict__ a_d) {
  __shared__ float xs[64 * 128];           // 32 KB
  int t = threadIdx.x;
  int n0 = blockIdx.x * 64;
  {
    const float4* xg = (const float4*)(x + (size_t)n0 * 128);
    float4* xs4 = (float4*)xs;
#pragma unroll
    for (int i = 0; i < 8; i++) xs4[t + i * 256] = xg[t + i * 256];
  }
  __syncthreads();

  int lane = t & 63;
  int g = t >> 6;                 // wave id = m-group
  int c0 = lane * 2;              // column pair
  const float4* xs4 = (const float4*)(xs + (size_t)g * 16 * 128);

  float2 acc[16];
#pragma unroll
  for (int j = 0; j < 16; j++) acc[j] = make_float2(0.f, 0.f);

  for (int k4 = 0; k4 < 32; k4++) {
    float2 w0 = *(const float2*)(W1 + (size_t)(4 * k4 + 0) * 128 + c0);
    float2 w1 = *(const float2*)(W1 + (size_t)(4 * k4 + 1) * 128 + c0);
    float2 w2 = *(const float2*)(W1 + (size_t)(4 * k4 + 2) * 128 + c0);
    float2 w3 = *(const float2*)(W1 + (size_t)(4 * k4 + 3) * 128 + c0);
#pragma unroll
    for (int j = 0; j < 16; j++) {
      float4 xv = xs4[j * 32 + k4];           // wave-uniform -> LDS broadcast
      acc[j].x = fmaf(xv.x, w0.x, acc[j].x);
      acc[j].y = fmaf(xv.x, w0.y, acc[j].y);
      acc[j].x = fmaf(xv.y, w1.x, acc[j].x);
      acc[j].y = fmaf(xv.y, w1.y, acc[j].y);
      acc[j].x = fmaf(xv.z, w2.x, acc[j].x);
      acc[j].y = fmaf(xv.z, w2.y, acc[j].y);
      acc[j].x = fmaf(xv.w, w3.x, acc[j].x);
      acc[j].y = fmaf(xv.w, w3.y, acc[j].y);
    }
  }

  float2 av_s = *(const float2*)(asv + c0);
  float2 av_d = *(const float2*)(adv + c0);
  int head = lane >> 5;
#pragma unroll 4
  for (int j = 0; j < 16; j++) {
    int n = n0 + g * 16 + j;
    __hip_bfloat162 hv;
    hv.x = __float2bfloat16(acc[j].x);
    hv.y = __float2bfloat16(acc[j].y);
    *(__hip_bfloat162*)(h1b + (size_t)n * 128 + c0) = hv;
    float rs = half_red_sum(acc[j].x * av_s.x + acc[j].y * av_s.y);
    float rd = half_red_sum(acc[j].x * av_d.x + acc[j].y * av_d.y);
    if ((lane & 31) == 0) {
      a_s[n * 2 + head] = rs;
      a_d[n * 2 + head] = rd;
    }
  }
}

// ---------------- Layer 1 agg (single pass) + ELU + fused layer-2 GEMM ----------------
__global__ __launch_bounds__(128) void k_agg1(
    const int* __restrict__ off, const int* __restrict__ csr_src,
    const float* __restrict__ a_s, const float* __restrict__ a_d,
    const __hip_bfloat16* __restrict__ h1b, const float* __restrict__ b1,
    const float* __restrict__ W2, const float* __restrict__ as2,
    const float* __restrict__ ad2,
    float* __restrict__ h2, float* __restrict__ a_s2, float* __restrict__ a_d2) {
  int v = blockIdx.x;
  int t = threadIdx.x;
  int h = t >> 6, lane = t & 63;
  int beg = off[v], end = off[v + 1];
  float2 advv = *(const float2*)(a_d + 2 * v);
  float adh = h ? advv.y : advv.x;

  float sum = 0.f;
  float acc0 = 0.f, acc1 = 0.f, acc2 = 0.f, acc3 = 0.f;
  int i = beg;
  for (; i + 4 <= end; i += 4) {
    int s0 = csr_src[i], s1 = csr_src[i + 1], s2 = csr_src[i + 2], s3 = csr_src[i + 3];
    float2 A0 = *(const float2*)(a_s + 2 * s0);
    float2 A1 = *(const float2*)(a_s + 2 * s1);
    float2 A2 = *(const float2*)(a_s + 2 * s2);
    float2 A3 = *(const float2*)(a_s + 2 * s3);
    float e0 = (h ? A0.y : A0.x) + adh; e0 = (e0 >= 0.f) ? e0 : 0.2f * e0;
    float e1 = (h ? A1.y : A1.x) + adh; e1 = (e1 >= 0.f) ? e1 : 0.2f * e1;
    float e2 = (h ? A2.y : A2.x) + adh; e2 = (e2 >= 0.f) ? e2 : 0.2f * e2;
    float e3 = (h ? A3.y : A3.x) + adh; e3 = (e3 >= 0.f) ? e3 : 0.2f * e3;
    float x0 = __expf(e0), x1 = __expf(e1), x2 = __expf(e2), x3 = __expf(e3);
    sum += (x0 + x1) + (x2 + x3);
    acc0 = fmaf(x0, __bfloat162float(h1b[(size_t)s0 * 128 + t]), acc0);
    acc1 = fmaf(x1, __bfloat162float(h1b[(size_t)s1 * 128 + t]), acc1);
    acc2 = fmaf(x2, __bfloat162float(h1b[(size_t)s2 * 128 + t]), acc2);
    acc3 = fmaf(x3, __bfloat162float(h1b[(size_t)s3 * 128 + t]), acc3);
  }
  for (; i < end; i++) {
    int s = csr_src[i];
    float2 A = *(const float2*)(a_s + 2 * s);
    float e = (h ? A.y : A.x) + adh; e = (e >= 0.f) ? e : 0.2f * e;
    float ex = __expf(e);
    sum += ex;
    acc0 = fmaf(ex, __bfloat162float(h1b[(size_t)s * 128 + t]), acc0);
  }
  float acc = (acc0 + acc1) + (acc2 + acc3);
  float inv = 1.f / (sum + 1e-16f);
  float o = acc * inv + b1[t];
  o = (o > 0.f) ? o : expm1f(o);   // ELU

  float4 w2v = *(const float4*)(W2 + t * 4);
  float p0 = wave_red_sum(o * w2v.x);
  float p1 = wave_red_sum(o * w2v.y);
  float p2 = wave_red_sum(o * w2v.z);
  float p3 = wave_red_sum(o * w2v.w);
  __shared__ float red[8];
  if (lane == 0) { red[h * 4 + 0] = p0; red[h * 4 + 1] = p1; red[h * 4 + 2] = p2; red[h * 4 + 3] = p3; }
  __syncthreads();
  if (t == 0) {
    float q0 = red[0] + red[4], q1 = red[1] + red[5];
    float q2 = red[2] + red[6], q3 = red[3] + red[7];
    float4 q = {q0, q1, q2, q3};
    *(float4*)(h2 + (size_t)v * 4) = q;
    a_s2[v] = q0 * as2[0] + q1 * as2[1] + q2 * as2[2] + q3 * as2[3];
    a_d2[v] = q0 * ad2[0] + q1 * ad2[1] + q2 * ad2[2] + q3 * ad2[3];
  }
}

// ---------------- Layer 2: fused segment softmax + aggregation + row softmax ----------------
__global__ __launch_bounds__(256) void k_agg2(
    const int* __restrict__ off, const int* __restrict__ csr_src,
    const float* __restrict__ a_s, const float* __restrict__ a_d,
    const float* __restrict__ h2, const float* __restrict__ b2,
    float* __restrict__ out) {
  int v = blockIdx.x * 4 + (threadIdx.x >> 6);
  int lane = threadIdx.x & 63;
  int beg = off[v], end = off[v + 1];
  float adv = a_d[v];

  float sum = 0.f;
  float4 acc = {0.f, 0.f, 0.f, 0.f};
  for (int i = beg + lane; i < end; i += 64) {
    int s = csr_src[i];
    float e = a_s[s] + adv;
    e = (e >= 0.f) ? e : 0.2f * e;
    float ex = __expf(e);
    sum += ex;
    float4 hv = *(const float4*)(h2 + (size_t)s * 4);
    acc.x = fmaf(ex, hv.x, acc.x);
    acc.y = fmaf(ex, hv.y, acc.y);
    acc.z = fmaf(ex, hv.z, acc.z);
    acc.w = fmaf(ex, hv.w, acc.w);
  }
  sum = wave_red_sum(sum);
  acc.x = wave_red_sum(acc.x);
  acc.y = wave_red_sum(acc.y);
  acc.z = wave_red_sum(acc.z);
  acc.w = wave_red_sum(acc.w);

  if (lane == 0) {
    float invd = 1.f / (sum + 1e-16f);
    float o0 = acc.x * invd + b2[0];
    float o1 = acc.y * invd + b2[1];
    float o2 = acc.z * invd + b2[2];
    float o3 = acc.w * invd + b2[3];
    float mx = fmaxf(fmaxf(o0, o1), fmaxf(o2, o3));
    float e0 = __expf(o0 - mx), e1 = __expf(o1 - mx);
    float e2 = __expf(o2 - mx), e3 = __expf(o3 - mx);
    float s4 = e0 + e1 + e2 + e3;
    float4 r = {e0 / s4, e1 / s4, e2 / s4, e3 / s4};
    *(float4*)(out + (size_t)v * 4) = r;
  }
}

extern "C" void kernel_launch(void* const* d_in, const int* in_sizes, int n_in,
                              void* d_out, int out_size, void* d_ws, size_t ws_size,
                              hipStream_t stream) {
  const float* x   = (const float*)d_in[0];
  const int*   ei  = (const int*)d_in[1];   // [2, E]: row0 = src, row1 = dst
  const float* W1  = (const float*)d_in[3];
  const float* as1 = (const float*)d_in[4];
  const float* ad1 = (const float*)d_in[5];
  const float* b1  = (const float*)d_in[6];
  const float* W2  = (const float*)d_in[7];
  const float* as2 = (const float*)d_in[8];
  const float* ad2 = (const float*)d_in[9];
  const float* b2  = (const float*)d_in[10];
  float* out = (float*)d_out;

  char* w = (char*)d_ws;
  auto alloc = [&](size_t bytes) {
    char* p = w;
    w += (bytes + 255) & ~(size_t)255;
    return p;
  };
  int*   deg     = (int*)alloc((size_t)N_NODES * 4);
  int*   off     = (int*)alloc((size_t)(N_NODES + 1) * 4);
  int*   cur     = (int*)alloc((size_t)N_NODES * 4);
  int*   csr_src = (int*)alloc((size_t)ET * 4);
  int*   blocksum= (int*)alloc((size_t)SCAN_BLOCKS * 4);
  __hip_bfloat16* h1b = (__hip_bfloat16*)alloc((size_t)N_NODES * 128 * 2);
  float* a_s1w   = (float*)alloc((size_t)N_NODES * 2 * 4);
  float* a_d1w   = (float*)alloc((size_t)N_NODES * 2 * 4);
  float* h2      = (float*)alloc((size_t)N_NODES * 4 * 4);
  float* a_s2w   = (float*)alloc((size_t)N_NODES * 4);
  float* a_d2w   = (float*)alloc((size_t)N_NODES * 4);

  hipMemsetAsync(deg, 0, (size_t)N_NODES * 4, stream);
  k_hist<<<(ET + 255) / 256, 256, 0, stream>>>(ei, deg);
  k_scanA<<<SCAN_BLOCKS, 1024, 0, stream>>>(deg, blocksum);
  k_scanB<<<SCAN_BLOCKS, 1024, 0, stream>>>(deg, blocksum, off, cur);
  k_fill<<<(ET + 255) / 256, 256, 0, stream>>>(ei, cur, csr_src);

  k_gemm1<<<N_NODES / 64, 256, 0, stream>>>(x, W1, as1, ad1, h1b, a_s1w, a_d1w);
  k_agg1<<<N_NODES, 128, 0, stream>>>(off, csr_src, a_s1w, a_d1w, h1b, b1,
                                      W2, as2, ad2, h2, a_s2w, a_d2w);
  k_agg2<<<N_NODES / 4, 256, 0, stream>>>(off, csr_src, a_s2w, a_d2w, h2, b2, out);
}